// Round 8
// baseline (250.738 us; speedup 1.0000x reference)
//
#include <hip/hip_runtime.h>
#include <hip/hip_bf16.h>

// ---------------------------------------------------------------------------
// 2-layer GraphConv (DGL norm='both') + mean_nodes pool + linear classifier.
// N=80000, E=1.28M, D=H=64, C=5, G=512.
// R7->R8: agg+GEMM fused into layer_kernel (block = 64 nodes). Each wave
// interleaves 4 nodes per round (4 col loads + 16 row loads all independent)
// -- R7 post-mortem showed per-wave MLP was degree-bound (mean indeg 16 =>
// only 2 loads in flight), with nodes processed serially; 4-node interleave
// overlaps the per-node latency chains. Cross-sub reduce via role-swap
// butterfly (56 shfl vs 96). Agg sums go to LDS; same block then runs the
// 64x64 bf16 MFMA tile + relu/norm epilogue. 10 -> 8 dispatches; s1/s2
// intermediate buffers eliminated.
// ---------------------------------------------------------------------------

#define NBK 160            // max buckets: ceil(80000/512)=157 <= 160
#define HB  256            // histogram blocks in p1

typedef __attribute__((ext_vector_type(8))) short bf16x8;
typedef __attribute__((ext_vector_type(4))) float f32x4;

__device__ __forceinline__ float bflo(unsigned u) { return __uint_as_float(u << 16); }
__device__ __forceinline__ float bfhi(unsigned u) { return __uint_as_float(u & 0xffff0000u); }
__device__ __forceinline__ float bf1(unsigned short u) { return __uint_as_float((unsigned)u << 16); }
__device__ __forceinline__ unsigned short f2bf(float f) {   // RNE
    unsigned u = __float_as_uint(f);
    return (unsigned short)((u + 0x7fff + ((u >> 16) & 1)) >> 16);
}
__device__ __forceinline__ unsigned packbf(float lo, float hi) {
    return (unsigned)f2bf(lo) | ((unsigned)f2bf(hi) << 16);
}

// --- P1: per-block bucket histograms (blocks < HB) + graph bounds (rest) ---
__global__ __launch_bounds__(256) void p1_hist(
    const int* __restrict__ src, const int* __restrict__ dst,
    int* __restrict__ histD, int* __restrict__ histS,
    const int* __restrict__ gids, int* __restrict__ goffs,
    int E, int NB, int N, int G)
{
    if (blockIdx.x >= HB) {                  // fused bounds_kernel
        int i = (blockIdx.x - HB) * 256 + threadIdx.x;
        if (i >= N) return;
        int b = gids[i];
        if (i == 0) {
            for (int g = 0; g <= b; g++) goffs[g] = 0;
        } else {
            int a = gids[i - 1];
            for (int g = a + 1; g <= b; g++) goffs[g] = i;
        }
        if (i == N - 1) {
            for (int g = b + 1; g <= G; g++) goffs[g] = N;
        }
        return;
    }
    __shared__ int hd[NBK], hs[NBK];
    for (int i = threadIdx.x; i < NB; i += 256) { hd[i] = 0; hs[i] = 0; }
    __syncthreads();
    int chunk = (E + HB - 1) / HB;
    int s0 = blockIdx.x * chunk, s1 = min(E, s0 + chunk);
    for (int i = s0 + threadIdx.x; i < s1; i += 256) {
        atomicAdd(&hd[dst[i] >> 9], 1);
        atomicAdd(&hs[src[i] >> 9], 1);
    }
    __syncthreads();
    for (int b = threadIdx.x; b < NB; b += 256) {
        histD[b * 256 + blockIdx.x] = hd[b];
        histS[b * 256 + blockIdx.x] = hs[b];
    }
}

// --- P2: per-bucket exclusive scan over the 256 block counts (in-place) ----
__global__ __launch_bounds__(256) void p2_scanblocks(
    int* __restrict__ histD, int* __restrict__ histS,
    int* __restrict__ btotD, int* __restrict__ btotS, int NB)
{
    int b = blockIdx.x;
    bool dmode = b < NB;
    int* h = dmode ? (histD + b * 256) : (histS + (b - NB) * 256);
    int t = threadIdx.x, lane = t & 63, w = t >> 6;
    int v = h[t];
    int x = v;
    #pragma unroll
    for (int off = 1; off < 64; off <<= 1) {
        int y = __shfl_up(x, off);
        if (lane >= off) x += y;
    }
    __shared__ int wt[4];
    if (lane == 63) wt[w] = x;
    __syncthreads();
    int bw = 0;
    for (int i = 0; i < w; i++) bw += wt[i];
    h[t] = x - v + bw;                       // exclusive
    if (t == 255) (dmode ? btotD : btotS)[dmode ? b : b - NB] = x + bw;
}

// --- P3: scan bucket totals -> bucket bases (single block) -----------------
__global__ __launch_bounds__(256) void p3_scanbuckets(
    const int* __restrict__ btotD, const int* __restrict__ btotS,
    int* __restrict__ baseD, int* __restrict__ baseS,
    int* __restrict__ row_offs, int E, int NB, int N)
{
    __shared__ int wt[4];
    int t = threadIdx.x, lane = t & 63, w = t >> 6;
    int v = (t < NB) ? btotD[t] : 0;
    int x = v;
    #pragma unroll
    for (int off = 1; off < 64; off <<= 1) {
        int y = __shfl_up(x, off);
        if (lane >= off) x += y;
    }
    if (lane == 63) wt[w] = x;
    __syncthreads();
    int bw = 0;
    for (int i = 0; i < w; i++) bw += wt[i];
    if (t <= NB) baseD[t] = x - v + bw;
    __syncthreads();
    v = (t < NB) ? btotS[t] : 0;
    x = v;
    #pragma unroll
    for (int off = 1; off < 64; off <<= 1) {
        int y = __shfl_up(x, off);
        if (lane >= off) x += y;
    }
    if (lane == 63) wt[w] = x;
    __syncthreads();
    bw = 0;
    for (int i = 0; i < w; i++) bw += wt[i];
    if (t <= NB) baseS[t] = x - v + bw;
    if (t == 0) row_offs[N] = E;
}

// --- P4: scatter edges into dst-buckets (packed) + src locals --------------
__global__ __launch_bounds__(256) void p4_scatter(
    const int* __restrict__ src, const int* __restrict__ dst,
    const int* __restrict__ histD, const int* __restrict__ histS,
    const int* __restrict__ baseD, const int* __restrict__ baseS,
    int* __restrict__ pack, unsigned short* __restrict__ sloc, int E, int NB)
{
    __shared__ int cd[NBK], cs[NBK];
    for (int b = threadIdx.x; b < NB; b += 256) {
        cd[b] = baseD[b] + histD[b * 256 + blockIdx.x];
        cs[b] = baseS[b] + histS[b * 256 + blockIdx.x];
    }
    __syncthreads();
    int chunk = (E + gridDim.x - 1) / gridDim.x;
    int s0 = blockIdx.x * chunk, s1 = min(E, s0 + chunk);
    for (int i = s0 + threadIdx.x; i < s1; i += 256) {
        int s = src[i], d = dst[i];
        int pd = atomicAdd(&cd[d >> 9], 1);          // LDS atomic
        pack[pd] = ((d & 511) << 17) | s;
        int ps = atomicAdd(&cs[s >> 9], 1);          // LDS atomic
        sloc[ps] = (unsigned short)(s & 511);
    }
}

// --- P5: dst mode -> CSR (row_offs,col,ndst); src mode -> nsrc + prescale --
__global__ __launch_bounds__(256) void p5_build(
    const int* __restrict__ pack, const unsigned short* __restrict__ sloc,
    const int* __restrict__ baseD, const int* __restrict__ baseS,
    int* __restrict__ col, int* __restrict__ row_offs,
    float* __restrict__ nsrc, float* __restrict__ ndst,
    const float* __restrict__ h, unsigned short* __restrict__ xs,
    int N, int NB)
{
    __shared__ int hist[512];
    __shared__ float nsl[512];
    __shared__ int wt[4];
    int t = threadIdx.x;
    bool dmode = blockIdx.x < NB;
    int b = dmode ? blockIdx.x : blockIdx.x - NB;
    int n0 = b << 9, n1 = min(N, n0 + 512);
    hist[t] = 0; hist[t + 256] = 0;
    __syncthreads();
    int e0 = dmode ? baseD[b] : baseS[b];
    int e1 = dmode ? baseD[b + 1] : baseS[b + 1];
    if (!dmode) {
        for (int i = e0 + t; i < e1; i += 256)
            atomicAdd(&hist[sloc[i]], 1);            // LDS atomic
        __syncthreads();
        for (int n = n0 + t; n < n1; n += 256) {
            float s = rsqrtf((float)max(hist[n - n0], 1));
            nsrc[n] = s;
            nsl[n - n0] = s;
        }
        __syncthreads();
        int cnt = n1 - n0;
        const float2* h2p = (const float2*)h;
        ushort2* xp = (ushort2*)xs;
        for (int i = t; i < cnt * 32; i += 256) {
            int node = i >> 5;
            float s = nsl[node];
            float2 v = h2p[(size_t)(n0 + node) * 32 + (i & 31)];
            ushort2 o;
            o.x = f2bf(v.x * s);
            o.y = f2bf(v.y * s);
            xp[(size_t)(n0 + node) * 32 + (i & 31)] = o;
        }
        return;
    }
    for (int i = e0 + t; i < e1; i += 256)
        atomicAdd(&hist[pack[i] >> 17], 1);          // LDS atomic
    __syncthreads();
    int c0 = hist[2 * t], c1 = hist[2 * t + 1];
    int v = c0 + c1;
    int lane = t & 63, w = t >> 6;
    int x = v;
    #pragma unroll
    for (int off = 1; off < 64; off <<= 1) {
        int y = __shfl_up(x, off);
        if (lane >= off) x += y;
    }
    if (lane == 63) wt[w] = x;
    __syncthreads();
    int bw = 0;
    for (int i = 0; i < w; i++) bw += wt[i];
    int excl = x - v + bw;
    int n = n0 + 2 * t;
    if (n < n1) {
        row_offs[n] = e0 + excl;
        ndst[n] = rsqrtf((float)max(c0, 1));
    }
    if (n + 1 < n1) {
        row_offs[n + 1] = e0 + excl + c0;
        ndst[n + 1] = rsqrtf((float)max(c1, 1));
    }
    hist[2 * t] = excl;
    hist[2 * t + 1] = excl + c0;
    __syncthreads();
    for (int i = e0 + t; i < e1; i += 256) {
        int wd = pack[i];
        int pos = atomicAdd(&hist[wd >> 17], 1);     // LDS atomic
        col[e0 + pos] = wd & 0x1FFFF;
    }
}

// --- fused layer: gather-sum (4-node interleave) -> LDS -> MFMA -> epilogue -
// block = 64 consecutive nodes, 4 waves; wave w owns rows w*16..w*16+15,
// processed in 4 rounds of 4 interleaved nodes. Butterfly role-swap reduce
// leaves node (sub&3)'s full sums on each sub-group; subs 0..3 write LDS.
__global__ __launch_bounds__(256) void layer_kernel(
    const unsigned short* __restrict__ x,    // gather table, N x 64 bf16
    const int* __restrict__ col, const int* __restrict__ row_offs,
    const float* __restrict__ W, const float* __restrict__ b,
    const float* __restrict__ ndst, const float* __restrict__ nsrc,
    unsigned short* __restrict__ y,          // N x 64 bf16 out
    int N, int scale_out)
{
    __shared__ __align__(16) unsigned short As[64][72];   // +8 pad: bank spread
    int t = threadIdx.x, lane = t & 63, w = t >> 6;
    int sub = lane >> 3, li = lane & 7;
    int c16 = lane & 15, quad = lane >> 4;
    const uint4* x4 = (const uint4*)x;

    // B fragments + bias (W fp32 -> bf16)
    bf16x8 bfrag[4][2];
    #pragma unroll
    for (int nt = 0; nt < 4; nt++)
        #pragma unroll
        for (int ks = 0; ks < 2; ks++)
            #pragma unroll
            for (int j = 0; j < 8; j++)
                bfrag[nt][ks][j] =
                    (short)f2bf(W[(ks * 32 + quad * 8 + j) * 64 + nt * 16 + c16]);
    float bias[4];
    #pragma unroll
    for (int nt = 0; nt < 4; nt++) bias[nt] = b[nt * 16 + c16];

    int nblk = blockIdx.x * 64;

    #pragma unroll 1
    for (int r = 0; r < 4; r++) {
        int nb = nblk + w * 16 + r * 4;      // first of this round's 4 nodes
        int rv = 0;
        if (lane < 5) rv = row_offs[min(nb + lane, N)];
        int ro[4], cn[4];
        #pragma unroll
        for (int j = 0; j < 4; j++) {
            ro[j] = __shfl(rv, j);
            int nxt = __shfl(rv, j + 1);
            cn[j] = (nb + j < N) ? (nxt - ro[j]) : 0;
        }
        int idx0 = 0, idx1 = 0, idx2 = 0, idx3 = 0;
        if (lane < cn[0]) idx0 = col[ro[0] + lane];
        if (lane < cn[1]) idx1 = col[ro[1] + lane];
        if (lane < cn[2]) idx2 = col[ro[2] + lane];
        if (lane < cn[3]) idx3 = col[ro[3] + lane];

        float A[4][8];
        #pragma unroll
        for (int j = 0; j < 4; j++)
            #pragma unroll
            for (int k = 0; k < 8; k++) A[j][k] = 0.f;

        bool fast = (cn[0] <= 32) & (cn[1] <= 32) & (cn[2] <= 32) & (cn[3] <= 32);
        if (fast) {
            #pragma unroll
            for (int j = 0; j < 4; j++) {
                int idx = j == 0 ? idx0 : j == 1 ? idx1 : j == 2 ? idx2 : idx3;
                int c = cn[j];
                int cm = max(c - 1, 0);
                int e0 = sub, e1 = 8 + sub, e2 = 16 + sub, e3 = 24 + sub;
                int s0 = __shfl(idx, min(e0, cm));
                int s1 = __shfl(idx, min(e1, cm));
                int s2 = __shfl(idx, min(e2, cm));
                int s3 = __shfl(idx, min(e3, cm));
                uint4 v0 = make_uint4(0u,0u,0u,0u), v1 = v0, v2 = v0, v3 = v0;
                if (e0 < c) v0 = x4[(size_t)s0 * 8 + li];
                if (e1 < c) v1 = x4[(size_t)s1 * 8 + li];
                if (e2 < c) v2 = x4[(size_t)s2 * 8 + li];
                if (e3 < c) v3 = x4[(size_t)s3 * 8 + li];
                A[j][0] += bflo(v0.x) + bflo(v1.x) + bflo(v2.x) + bflo(v3.x);
                A[j][1] += bfhi(v0.x) + bfhi(v1.x) + bfhi(v2.x) + bfhi(v3.x);
                A[j][2] += bflo(v0.y) + bflo(v1.y) + bflo(v2.y) + bflo(v3.y);
                A[j][3] += bfhi(v0.y) + bfhi(v1.y) + bfhi(v2.y) + bfhi(v3.y);
                A[j][4] += bflo(v0.z) + bflo(v1.z) + bflo(v2.z) + bflo(v3.z);
                A[j][5] += bfhi(v0.z) + bfhi(v1.z) + bfhi(v2.z) + bfhi(v3.z);
                A[j][6] += bflo(v0.w) + bflo(v1.w) + bflo(v2.w) + bflo(v3.w);
                A[j][7] += bfhi(v0.w) + bfhi(v1.w) + bfhi(v2.w) + bfhi(v3.w);
            }
        } else {                              // rare: any indeg > 32
            #pragma unroll
            for (int j = 0; j < 4; j++) {
                int idx = j == 0 ? idx0 : j == 1 ? idx1 : j == 2 ? idx2 : idx3;
                int c = cn[j], roj = ro[j];
                for (int cc = 0; cc < c; cc += 64) {
                    int m = min(c - cc, 64);
                    if (cc > 0) idx = (lane < m) ? col[roj + cc + lane] : 0;
                    for (int i = 0; i < m; i += 8) {
                        int e = i + sub;
                        int s = __shfl(idx, min(e, m - 1));
                        if (e < m) {
                            uint4 v = x4[(size_t)s * 8 + li];
                            A[j][0] += bflo(v.x); A[j][1] += bfhi(v.x);
                            A[j][2] += bflo(v.y); A[j][3] += bfhi(v.y);
                            A[j][4] += bflo(v.z); A[j][5] += bfhi(v.z);
                            A[j][6] += bflo(v.w); A[j][7] += bfhi(v.w);
                        }
                    }
                }
            }
        }
        // role-swap butterfly: sub s ends holding full sums of node s&3
        bool o1 = (sub & 1), o2 = (sub & 2);
        float D[8];
        #pragma unroll
        for (int k = 0; k < 8; k++) {
            float u0 = __shfl_xor(A[0][k], 8);
            float u1 = __shfl_xor(A[1][k], 8);
            float u2 = __shfl_xor(A[2][k], 8);
            float u3 = __shfl_xor(A[3][k], 8);
            float b0 = o1 ? (A[1][k] + u1) : (A[0][k] + u0);  // node  s&1
            float b1 = o1 ? (A[3][k] + u3) : (A[2][k] + u2);  // node 2+(s&1)
            float v0 = __shfl_xor(b0, 16);
            float v1 = __shfl_xor(b1, 16);
            float c  = o2 ? (b1 + v1) : (b0 + v0);            // node  s&3
            D[k] = c + __shfl_xor(c, 32);
        }
        if (sub < 4) {
            int rowi = w * 16 + r * 4 + sub;
            uint4 o;
            o.x = packbf(D[0], D[1]);
            o.y = packbf(D[2], D[3]);
            o.z = packbf(D[4], D[5]);
            o.w = packbf(D[6], D[7]);
            *(uint4*)&As[rowi][li * 8] = o;
        }
    }
    __syncthreads();

    // MFMA on own 16 rows: A frag = As[w*16 + (lane&15)][k], k = ks*32+quad*8+j
    union { uint4 u; bf16x8 v; } a0, a1;
    a0.u = *(const uint4*)&As[w * 16 + c16][quad * 8];
    a1.u = *(const uint4*)&As[w * 16 + c16][32 + quad * 8];
    float nd[4], ns[4];
    #pragma unroll
    for (int rr = 0; rr < 4; rr++) {
        int m = min(nblk + w * 16 + quad * 4 + rr, N - 1);
        nd[rr] = ndst[m];
        ns[rr] = scale_out ? nsrc[m] : 1.f;
    }
    #pragma unroll
    for (int nt = 0; nt < 4; nt++) {
        f32x4 acc = {0.f, 0.f, 0.f, 0.f};
        acc = __builtin_amdgcn_mfma_f32_16x16x32_bf16(a0.v, bfrag[nt][0], acc, 0, 0, 0);
        acc = __builtin_amdgcn_mfma_f32_16x16x32_bf16(a1.v, bfrag[nt][1], acc, 0, 0, 0);
        #pragma unroll
        for (int rr = 0; rr < 4; rr++) {
            int m = nblk + w * 16 + quad * 4 + rr;
            if (m < N)
                y[(size_t)m * 64 + nt * 16 + c16] =
                    f2bf(fmaxf(nd[rr] * acc[rr] + bias[nt], 0.f) * ns[rr]);
        }
    }
}

// --- per-graph mean pool + 64x5 classifier (block per graph) ---------------
__global__ __launch_bounds__(256) void pool_kernel(
    const unsigned short* __restrict__ h2, const int* __restrict__ goffs,
    const float* __restrict__ Wc, const float* __restrict__ bc,
    float* __restrict__ out)
{
    int g = blockIdx.x;
    int lane = threadIdx.x & 63;
    int w = threadIdx.x >> 6;
    int s = goffs[g], e = goffs[g + 1];
    float acc = 0.f;
    for (int i = s + w; i < e; i += 4) acc += bf1(h2[i * 64 + lane]);
    __shared__ float red[4][64];
    red[w][lane] = acc;
    __syncthreads();
    if (w == 0) {
        float tot = red[0][lane] + red[1][lane] + red[2][lane] + red[3][lane];
        float mean = tot / (float)max(e - s, 1);
        float wc[5];
        #pragma unroll
        for (int c = 0; c < 5; c++) wc[c] = Wc[lane * 5 + c];
        #pragma unroll
        for (int c = 0; c < 5; c++) {
            float p = mean * wc[c];
            #pragma unroll
            for (int off = 32; off; off >>= 1) p += __shfl_down(p, off);
            if (lane == 0) out[g * 5 + c] = p + bc[c];
        }
    }
}

extern "C" void kernel_launch(void* const* d_in, const int* in_sizes, int n_in,
                              void* d_out, int out_size, void* d_ws, size_t ws_size,
                              hipStream_t stream)
{
    const float* h    = (const float*)d_in[0];
    const int*   src  = (const int*)d_in[1];
    const int*   dst  = (const int*)d_in[2];
    const int*   gids = (const int*)d_in[3];
    const float* W1   = (const float*)d_in[4];
    const float* b1   = (const float*)d_in[5];
    const float* W2   = (const float*)d_in[6];
    const float* b2   = (const float*)d_in[7];
    const float* Wc   = (const float*)d_in[8];
    const float* bc   = (const float*)d_in[9];
    float* out = (float*)d_out;

    const int N = in_sizes[0] / 64;
    const int E = in_sizes[1];
    const int G = out_size / 5;
    const int NB = (N + 511) >> 9;
    const int NBB = (N + 255) / 256;        // bounds blocks

    auto align = [](size_t x) { return (x + 255) & ~(size_t)255; };
    char* p = (char*)d_ws;
    int* histD   = (int*)p;            p += align((size_t)NBK * 256 * 4);
    int* histS   = (int*)p;            p += align((size_t)NBK * 256 * 4);
    int* btotD   = (int*)p;            p += align((size_t)NBK * 4);
    int* btotS   = (int*)p;            p += align((size_t)NBK * 4);
    int* baseD   = (int*)p;            p += align((size_t)(NBK + 1) * 4);
    int* baseS   = (int*)p;            p += align((size_t)(NBK + 1) * 4);
    int* row_offs= (int*)p;            p += align((size_t)(N + 1) * 4);
    float* nsrc  = (float*)p;          p += align((size_t)N * 4);
    float* ndst  = (float*)p;          p += align((size_t)N * 4);
    int* goffs   = (int*)p;            p += align((size_t)(G + 1) * 4);
    int* pack    = (int*)p;            p += align((size_t)E * 4);
    unsigned short* sloc = (unsigned short*)p; p += align((size_t)E * 2);
    int* col     = (int*)p;            p += align((size_t)E * 4);
    unsigned short* xs  = (unsigned short*)p; p += align((size_t)N * 64 * 2);
    unsigned short* h1s = (unsigned short*)p; p += align((size_t)N * 64 * 2);
    unsigned short* h2  = xs;   // alias: xs dead after layer1

    p1_hist<<<HB + NBB, 256, 0, stream>>>(src, dst, histD, histS,
                                          gids, goffs, E, NB, N, G);
    p2_scanblocks<<<2 * NB, 256, 0, stream>>>(histD, histS, btotD, btotS, NB);
    p3_scanbuckets<<<1, 256, 0, stream>>>(btotD, btotS, baseD, baseS,
                                          row_offs, E, NB, N);
    p4_scatter<<<256, 256, 0, stream>>>(src, dst, histD, histS, baseD, baseS,
                                        pack, sloc, E, NB);
    p5_build<<<2 * NB, 256, 0, stream>>>(pack, sloc, baseD, baseS, col,
                                         row_offs, nsrc, ndst, h, xs, N, NB);

    layer_kernel<<<(N + 63) / 64, 256, 0, stream>>>(
        xs, col, row_offs, W1, b1, ndst, nsrc, h1s, N, 1);
    layer_kernel<<<(N + 63) / 64, 256, 0, stream>>>(
        h1s, col, row_offs, W2, b2, ndst, nsrc, h2, N, 0);

    pool_kernel<<<G, 256, 0, stream>>>(h2, goffs, Wc, bc, out);
}

// Round 9
// 234.617 us; speedup vs baseline: 1.0687x; 1.0687x over previous
//
#include <hip/hip_runtime.h>
#include <hip/hip_bf16.h>

// ---------------------------------------------------------------------------
// 2-layer GraphConv (DGL norm='both') + mean_nodes pool + linear classifier.
// N=80000, E=1.28M, D=H=64, C=5, G=512.
// R8->R9: reverted R8's agg+GEMM fusion (occupancy collapsed 40%->16%:
// grid 1250 blocks + 4 serial rounds/wave destroyed TLP; split agg/gemm at
// 2048 blocks is faster). New: (a) single-pass CSR build -- fixed-capacity
// buckets (CAP = mean+11sigma) let each block reserve slots with one global
// atomicAdd per (block,bucket) (~80k atomics on 314 addrs), killing the
// p2/p3 scans and one full edge-list pass; CSR is padded, deg[] explicit.
// (b) agg prefetches next node's row_offs/deg/col one iteration ahead to
// break the per-node serial latency chain.
// ---------------------------------------------------------------------------

#define NBK 160            // max buckets: ceil(80000/512)=157 <= 160
#define HB  256            // edge-pass blocks in pA
#define CAP 9216           // per-bucket slot capacity (mean 8192, +11 sigma)

typedef __attribute__((ext_vector_type(8))) short bf16x8;
typedef __attribute__((ext_vector_type(4))) float f32x4;

__device__ __forceinline__ float bflo(unsigned u) { return __uint_as_float(u << 16); }
__device__ __forceinline__ float bfhi(unsigned u) { return __uint_as_float(u & 0xffff0000u); }
__device__ __forceinline__ float bf1(unsigned short u) { return __uint_as_float((unsigned)u << 16); }
__device__ __forceinline__ unsigned short f2bf(float f) {   // RNE
    unsigned u = __float_as_uint(f);
    return (unsigned short)((u + 0x7fff + ((u >> 16) & 1)) >> 16);
}
__device__ __forceinline__ unsigned packbf(float lo, float hi) {
    return (unsigned)f2bf(lo) | ((unsigned)f2bf(hi) << 16);
}

// --- pA: single-pass bucket scatter (blocks < HB) + graph bounds (rest) ----
// Per block: LDS-histogram its edge chunk, reserve per-bucket slots via one
// global atomicAdd per touched bucket, re-scan chunk (L2-hot) and scatter
// packed word (dstLocal<<17|src) and srcLocal into fixed-capacity buckets.
__global__ __launch_bounds__(256) void pA_scatter(
    const int* __restrict__ src, const int* __restrict__ dst,
    int* __restrict__ curD, int* __restrict__ curS,       // NBK cursors each, pre-zeroed
    int* __restrict__ pack, unsigned short* __restrict__ sloc,
    const int* __restrict__ gids, int* __restrict__ goffs,
    int E, int NB, int N, int G)
{
    if (blockIdx.x >= HB) {                  // fused bounds_kernel
        int i = (blockIdx.x - HB) * 256 + threadIdx.x;
        if (i >= N) return;
        int b = gids[i];
        if (i == 0) {
            for (int g = 0; g <= b; g++) goffs[g] = 0;
        } else {
            int a = gids[i - 1];
            for (int g = a + 1; g <= b; g++) goffs[g] = i;
        }
        if (i == N - 1) {
            for (int g = b + 1; g <= G; g++) goffs[g] = N;
        }
        return;
    }
    __shared__ int hd[NBK], hs[NBK];
    int t = threadIdx.x;
    for (int i = t; i < NB; i += 256) { hd[i] = 0; hs[i] = 0; }
    __syncthreads();
    int chunk = (E + HB - 1) / HB;
    int s0 = blockIdx.x * chunk, s1 = min(E, s0 + chunk);
    for (int i = s0 + t; i < s1; i += 256) {
        atomicAdd(&hd[dst[i] >> 9], 1);      // LDS atomic
        atomicAdd(&hs[src[i] >> 9], 1);      // LDS atomic
    }
    __syncthreads();
    // reserve global slots; hd/hs become this block's running cursors
    for (int b = t; b < NB; b += 256) {
        int cd = hd[b], cs = hs[b];
        hd[b] = cd ? atomicAdd(&curD[b], cd) : 0;   // device atomic, 1/bucket
        hs[b] = cs ? atomicAdd(&curS[b], cs) : 0;
    }
    __syncthreads();
    for (int i = s0 + t; i < s1; i += 256) { // chunk re-read is L2-hot
        int s = src[i], d = dst[i];
        int bd = d >> 9, bs = s >> 9;
        int pd = atomicAdd(&hd[bd], 1);      // LDS atomic
        int ps = atomicAdd(&hs[bs], 1);      // LDS atomic
        if (pd < CAP) pack[(size_t)bd * CAP + pd] = ((d & 511) << 17) | s;
        if (ps < CAP) sloc[(size_t)bs * CAP + ps] = (unsigned short)(s & 511);
    }
}

// --- p5: dst mode -> CSR (row_offs,deg,col,ndst); src mode -> nsrc+prescale -
__global__ __launch_bounds__(256) void p5_build(
    const int* __restrict__ pack, const unsigned short* __restrict__ sloc,
    const int* __restrict__ curD, const int* __restrict__ curS,
    int* __restrict__ col, int* __restrict__ row_offs, int* __restrict__ deg,
    float* __restrict__ nsrc, float* __restrict__ ndst,
    const float* __restrict__ h, unsigned short* __restrict__ xs,
    int N, int NB)
{
    __shared__ int hist[512];
    __shared__ float nsl[512];
    __shared__ int wt[4];
    int t = threadIdx.x;
    bool dmode = blockIdx.x < NB;
    int b = dmode ? blockIdx.x : blockIdx.x - NB;
    int n0 = b << 9, n1 = min(N, n0 + 512);
    hist[t] = 0; hist[t + 256] = 0;
    __syncthreads();
    int e0 = b * CAP;
    int tot = min(dmode ? curD[b] : curS[b], CAP);
    int e1 = e0 + tot;
    if (!dmode) {
        for (int i = e0 + t; i < e1; i += 256)
            atomicAdd(&hist[sloc[i]], 1);            // LDS atomic
        __syncthreads();
        for (int n = n0 + t; n < n1; n += 256) {
            float s = rsqrtf((float)max(hist[n - n0], 1));
            nsrc[n] = s;
            nsl[n - n0] = s;
        }
        __syncthreads();
        int cnt = n1 - n0;
        const float2* h2p = (const float2*)h;
        ushort2* xp = (ushort2*)xs;
        for (int i = t; i < cnt * 32; i += 256) {
            int node = i >> 5;
            float s = nsl[node];
            float2 v = h2p[(size_t)(n0 + node) * 32 + (i & 31)];
            ushort2 o;
            o.x = f2bf(v.x * s);
            o.y = f2bf(v.y * s);
            xp[(size_t)(n0 + node) * 32 + (i & 31)] = o;
        }
        return;
    }
    for (int i = e0 + t; i < e1; i += 256)
        atomicAdd(&hist[pack[i] >> 17], 1);          // LDS atomic
    __syncthreads();
    int c0 = hist[2 * t], c1 = hist[2 * t + 1];
    int v = c0 + c1;
    int lane = t & 63, w = t >> 6;
    int x = v;
    #pragma unroll
    for (int off = 1; off < 64; off <<= 1) {
        int y = __shfl_up(x, off);
        if (lane >= off) x += y;
    }
    if (lane == 63) wt[w] = x;
    __syncthreads();
    int bw = 0;
    for (int i = 0; i < w; i++) bw += wt[i];
    int excl = x - v + bw;
    int n = n0 + 2 * t;
    if (n < n1) {
        row_offs[n] = e0 + excl;
        deg[n] = c0;
        ndst[n] = rsqrtf((float)max(c0, 1));
    }
    if (n + 1 < n1) {
        row_offs[n + 1] = e0 + excl + c0;
        deg[n + 1] = c1;
        ndst[n + 1] = rsqrtf((float)max(c1, 1));
    }
    hist[2 * t] = excl;
    hist[2 * t + 1] = excl + c0;
    __syncthreads();
    for (int i = e0 + t; i < e1; i += 256) {
        int wd = pack[i];
        int pos = atomicAdd(&hist[wd >> 17], 1);     // LDS atomic
        col[e0 + pos] = wd & 0x1FFFF;
    }
}

// --- pure gather-sum with next-node prefetch -------------------------------
// one wave per node; sub=lane>>3 = edge slot, li=lane&7 = 16B chunk of the
// 128B row. Next iteration's row_offs/deg/col loaded during current reduce.
__global__ __launch_bounds__(256) void agg_kernel(
    const unsigned short* __restrict__ z, unsigned short* __restrict__ y,
    const int* __restrict__ col, const int* __restrict__ row_offs,
    const int* __restrict__ deg, int N)
{
    int lane = threadIdx.x & 63;
    int sub  = lane >> 3;
    int li   = lane & 7;
    const uint4* x4 = (const uint4*)z;

    int wid = (blockIdx.x * 256 + threadIdx.x) >> 6;
    int nw  = (gridDim.x * 256) >> 6;

    int ro = 0, cnt = 0, idx = 0;
    if (wid < N) {
        ro = row_offs[wid];
        cnt = deg[wid];
        if (lane < min(cnt, 64)) idx = col[ro + lane];
    }
    for (int node = wid; node < N; node += nw) {
        int nnode = node + nw;
        int nro = 0, ncnt = 0;
        if (nnode < N) { nro = row_offs[nnode]; ncnt = deg[nnode]; }  // prefetch

        float a0=0.f,a1=0.f,a2=0.f,a3=0.f,a4=0.f,a5=0.f,a6=0.f,a7=0.f;
        int cc = 0;
        int cidx = idx;
        while (cc < cnt) {
            int m = min(cnt - cc, 64);
            for (int i = 0; i < m; i += 32) {
                int e1 = i + sub, e2 = i + 8 + sub, e3 = i + 16 + sub, e4 = i + 24 + sub;
                int s1 = __shfl(cidx, min(e1, m - 1));
                int s2 = __shfl(cidx, min(e2, m - 1));
                int s3 = __shfl(cidx, min(e3, m - 1));
                int s4 = __shfl(cidx, min(e4, m - 1));
                uint4 v1 = make_uint4(0u,0u,0u,0u), v2 = v1, v3 = v1, v4 = v1;
                if (e1 < m) v1 = x4[(size_t)s1 * 8 + li];
                if (e2 < m) v2 = x4[(size_t)s2 * 8 + li];
                if (e3 < m) v3 = x4[(size_t)s3 * 8 + li];
                if (e4 < m) v4 = x4[(size_t)s4 * 8 + li];
                a0 += bflo(v1.x); a1 += bfhi(v1.x);
                a2 += bflo(v1.y); a3 += bfhi(v1.y);
                a4 += bflo(v1.z); a5 += bfhi(v1.z);
                a6 += bflo(v1.w); a7 += bfhi(v1.w);
                a0 += bflo(v2.x); a1 += bfhi(v2.x);
                a2 += bflo(v2.y); a3 += bfhi(v2.y);
                a4 += bflo(v2.z); a5 += bfhi(v2.z);
                a6 += bflo(v2.w); a7 += bfhi(v2.w);
                a0 += bflo(v3.x); a1 += bfhi(v3.x);
                a2 += bflo(v3.y); a3 += bfhi(v3.y);
                a4 += bflo(v3.z); a5 += bfhi(v3.z);
                a6 += bflo(v3.w); a7 += bfhi(v3.w);
                a0 += bflo(v4.x); a1 += bfhi(v4.x);
                a2 += bflo(v4.y); a3 += bfhi(v4.y);
                a4 += bflo(v4.z); a5 += bfhi(v4.z);
                a6 += bflo(v4.w); a7 += bfhi(v4.w);
            }
            cc += 64;
            if (cc < cnt) cidx = (lane < min(cnt - cc, 64)) ? col[ro + cc + lane] : 0;
        }
        // prefetch next node's col during the reduce
        idx = 0;
        if (nnode < N && lane < min(ncnt, 64)) idx = col[nro + lane];

        #pragma unroll
        for (int off = 8; off <= 32; off <<= 1) {
            a0 += __shfl_xor(a0, off); a1 += __shfl_xor(a1, off);
            a2 += __shfl_xor(a2, off); a3 += __shfl_xor(a3, off);
            a4 += __shfl_xor(a4, off); a5 += __shfl_xor(a5, off);
            a6 += __shfl_xor(a6, off); a7 += __shfl_xor(a7, off);
        }
        if (sub == 0) {                       // 8 lanes store the 128B row
            uint4 o;
            o.x = packbf(a0, a1);
            o.y = packbf(a2, a3);
            o.z = packbf(a4, a5);
            o.w = packbf(a6, a7);
            ((uint4*)y)[(size_t)node * 8 + li] = o;
        }
        ro = nro; cnt = ncnt;
    }
}

// --- GEMM + epilogue: Z[m] = relu(ndst[m]*(S[m]@W) + b) [* nsrc[m]] --------
__global__ __launch_bounds__(256) void gemm_kernel(
    const unsigned short* __restrict__ A, const float* __restrict__ W,
    const float* __restrict__ b, const float* __restrict__ ndst,
    const float* __restrict__ nsrc, unsigned short* __restrict__ Z,
    int M, int scale_out)
{
    int t = threadIdx.x, lane = t & 63, w = t >> 6;
    int col = lane & 15, quad = lane >> 4;
    bf16x8 bfrag[4][2];
    #pragma unroll
    for (int nt = 0; nt < 4; nt++)
        #pragma unroll
        for (int ks = 0; ks < 2; ks++)
            #pragma unroll
            for (int j = 0; j < 8; j++)
                bfrag[nt][ks][j] =
                    (short)f2bf(W[(ks * 32 + quad * 8 + j) * 64 + nt * 16 + col]);
    float bias[4];
    #pragma unroll
    for (int nt = 0; nt < 4; nt++) bias[nt] = b[nt * 16 + col];

    int mbase = blockIdx.x * 64 + w * 16;
    if (mbase >= M) return;
    int row = min(mbase + col, M - 1);
    const uint4* a4 = (const uint4*)A;
    union { uint4 u; bf16x8 v; } a0, a1;
    a0.u = a4[(size_t)row * 8 + quad];
    a1.u = a4[(size_t)row * 8 + 4 + quad];

    float nd[4], ns[4];
    #pragma unroll
    for (int r = 0; r < 4; r++) {
        int m = min(mbase + quad * 4 + r, M - 1);
        nd[r] = ndst[m];
        ns[r] = scale_out ? nsrc[m] : 1.f;
    }

    #pragma unroll
    for (int nt = 0; nt < 4; nt++) {
        f32x4 acc = {0.f, 0.f, 0.f, 0.f};
        acc = __builtin_amdgcn_mfma_f32_16x16x32_bf16(a0.v, bfrag[nt][0], acc, 0, 0, 0);
        acc = __builtin_amdgcn_mfma_f32_16x16x32_bf16(a1.v, bfrag[nt][1], acc, 0, 0, 0);
        #pragma unroll
        for (int r = 0; r < 4; r++) {
            int m = mbase + quad * 4 + r;
            if (m < M)
                Z[(size_t)m * 64 + nt * 16 + col] =
                    f2bf(fmaxf(nd[r] * acc[r] + bias[nt], 0.f) * ns[r]);
        }
    }
}

// --- per-graph mean pool + 64x5 classifier (block per graph) ---------------
__global__ __launch_bounds__(256) void pool_kernel(
    const unsigned short* __restrict__ h2, const int* __restrict__ goffs,
    const float* __restrict__ Wc, const float* __restrict__ bc,
    float* __restrict__ out)
{
    int g = blockIdx.x;
    int lane = threadIdx.x & 63;
    int w = threadIdx.x >> 6;
    int s = goffs[g], e = goffs[g + 1];
    float acc = 0.f;
    for (int i = s + w; i < e; i += 4) acc += bf1(h2[i * 64 + lane]);
    __shared__ float red[4][64];
    red[w][lane] = acc;
    __syncthreads();
    if (w == 0) {
        float tot = red[0][lane] + red[1][lane] + red[2][lane] + red[3][lane];
        float mean = tot / (float)max(e - s, 1);
        float wc[5];
        #pragma unroll
        for (int c = 0; c < 5; c++) wc[c] = Wc[lane * 5 + c];
        #pragma unroll
        for (int c = 0; c < 5; c++) {
            float p = mean * wc[c];
            #pragma unroll
            for (int off = 32; off; off >>= 1) p += __shfl_down(p, off);
            if (lane == 0) out[g * 5 + c] = p + bc[c];
        }
    }
}

extern "C" void kernel_launch(void* const* d_in, const int* in_sizes, int n_in,
                              void* d_out, int out_size, void* d_ws, size_t ws_size,
                              hipStream_t stream)
{
    const float* h    = (const float*)d_in[0];
    const int*   src  = (const int*)d_in[1];
    const int*   dst  = (const int*)d_in[2];
    const int*   gids = (const int*)d_in[3];
    const float* W1   = (const float*)d_in[4];
    const float* b1   = (const float*)d_in[5];
    const float* W2   = (const float*)d_in[6];
    const float* b2   = (const float*)d_in[7];
    const float* Wc   = (const float*)d_in[8];
    const float* bc   = (const float*)d_in[9];
    float* out = (float*)d_out;

    const int N = in_sizes[0] / 64;
    const int E = in_sizes[1];
    const int G = out_size / 5;
    const int NB = (N + 511) >> 9;
    const int NBB = (N + 255) / 256;        // bounds blocks

    auto align = [](size_t x) { return (x + 255) & ~(size_t)255; };
    char* p = (char*)d_ws;
    int* curD    = (int*)p;            p += align((size_t)2 * NBK * 4);
    int* curS    = curD + NBK;
    int* row_offs= (int*)p;            p += align((size_t)N * 4);
    int* deg     = (int*)p;            p += align((size_t)N * 4);
    float* nsrc  = (float*)p;          p += align((size_t)N * 4);
    float* ndst  = (float*)p;          p += align((size_t)N * 4);
    int* goffs   = (int*)p;            p += align((size_t)(G + 1) * 4);
    int* pack    = (int*)p;            p += align((size_t)NBK * CAP * 4);
    unsigned short* sloc = (unsigned short*)p; p += align((size_t)NBK * CAP * 2);
    int* col     = (int*)p;            p += align((size_t)NBK * CAP * 4);
    unsigned short* xs  = (unsigned short*)p; p += align((size_t)N * 64 * 2);
    unsigned short* s1  = (unsigned short*)p; p += align((size_t)N * 64 * 2);
    unsigned short* h1s = (unsigned short*)p; p += align((size_t)N * 64 * 2);
    unsigned short* s2  = s1;   // alias: s1 dead after gemm1
    unsigned short* h2  = xs;   // alias: xs dead after agg1

    hipMemsetAsync(curD, 0, (size_t)2 * NBK * 4, stream);

    pA_scatter<<<HB + NBB, 256, 0, stream>>>(src, dst, curD, curS, pack, sloc,
                                             gids, goffs, E, NB, N, G);
    p5_build<<<2 * NB, 256, 0, stream>>>(pack, sloc, curD, curS, col,
                                         row_offs, deg, nsrc, ndst, h, xs, N, NB);

    agg_kernel<<<2048, 256, 0, stream>>>(xs, s1, col, row_offs, deg, N);
    gemm_kernel<<<(N + 63) / 64, 256, 0, stream>>>(s1, W1, b1, ndst, nsrc,
                                                   h1s, N, 1);
    agg_kernel<<<2048, 256, 0, stream>>>(h1s, s2, col, row_offs, deg, N);
    gemm_kernel<<<(N + 63) / 64, 256, 0, stream>>>(s2, W2, b2, ndst, nsrc,
                                                   h2, N, 0);

    pool_kernel<<<G, 256, 0, stream>>>(h2, goffs, Wc, bc, out);
}